// Round 5
// baseline (1121.297 us; speedup 1.0000x reference)
//
#include <hip/hip_runtime.h>

#define TSTEPS 1024
#define BATCH 16384

typedef float f32x2 __attribute__((ext_vector_type(2)));

// Broadcast from lane ((lane&0x18)|K) within each aligned 8-lane group.
// Verified absmax 0.0 in rounds 2-4.
template<int K>
__device__ __forceinline__ float bc8(float v) {
    return __int_as_float(__builtin_amdgcn_ds_swizzle(__float_as_int(v), (K << 5) | 0x18));
}
// Exchange with lane^8 (combines the two half-lanes of a 16-lane group).
__device__ __forceinline__ float swz_xor8(float v) {
    return __int_as_float(__builtin_amdgcn_ds_swizzle(__float_as_int(v), 0x201F));
}
__device__ __forceinline__ f32x2 swz_xor8_2(f32x2 v) {
    f32x2 r; r.x = swz_xor8(v.x); r.y = swz_xor8(v.y); return r;
}
__device__ __forceinline__ float bperm(int addr, float v) {
    return __int_as_float(__builtin_amdgcn_ds_bpermute(addr, __float_as_int(v)));
}
__device__ __forceinline__ f32x2 fma2(f32x2 a, f32x2 b, f32x2 c) {
    return __builtin_elementwise_fma(a, b, c);   // v_pk_fma_f32
}
__device__ __forceinline__ f32x2 splat2(float v) { f32x2 r; r.x = v; r.y = v; return r; }

// Activations on PRE-SCALED z (weights folded with -log2e / -2log2e).
__device__ __forceinline__ float sig_s(float zs) {   // sigmoid(x), zs=-x*log2e
    return __builtin_amdgcn_rcpf(1.0f + __builtin_amdgcn_exp2f(zs));
}
__device__ __forceinline__ float tanh_s(float zs) {  // tanh(x), zs=-2x*log2e
    return __builtin_fmaf(2.0f, __builtin_amdgcn_rcpf(1.0f + __builtin_amdgcn_exp2f(zs)), -1.0f);
}
__device__ __forceinline__ float tanh_raw(float c) { return tanh_s(c * -2.88539008f); }

// 16 lanes per batch element: lane = (half, j). Lane owns k-range
// [half*4, half*4+4) of every gate-row dot product for hidden unit j.
__global__ __launch_bounds__(256, 4) void lstm2_fused(
    const float* __restrict__ x,
    const float* __restrict__ w_ih_l0, const float* __restrict__ w_hh_l0,
    const float* __restrict__ b_ih_l0, const float* __restrict__ b_hh_l0,
    const float* __restrict__ w_ih_l1, const float* __restrict__ w_hh_l1,
    const float* __restrict__ b_ih_l1, const float* __restrict__ b_hh_l1,
    const float* __restrict__ fc_w, const float* __restrict__ fc_b,
    float* __restrict__ out)
{
    const int tid  = blockIdx.x * blockDim.x + threadIdx.x;
    const int j    = tid & 7;
    const int half = (tid >> 3) & 1;
    const int b    = tid >> 4;
    const int lane = threadIdx.x & 63;

    // Gate order i,f,g,o. Pre-scale sigmoid rows by -log2e, tanh(g) by -2log2e.
    const float sc[4] = {-1.44269504f, -1.44269504f, -2.88539008f, -1.44269504f};

    // Packed weights: pair p holds gates (2p, 2p+1) in (x,y); k' = k - half*4.
    f32x2 wi0a[2], zb0p[2], zb1p[2];
    f32x2 wh0p[2][4], wi1p[2][4], wh1p[2][4];
#pragma unroll
    for (int p = 0; p < 2; ++p) {
        const int ga = 2 * p, gb = 2 * p + 1;
        const int ra = ga * 8 + j, rb = gb * 8 + j;
        const float sa = sc[ga], sb = sc[gb];
        wi0a[p].x = sa * w_ih_l0[ra * 2 + half];       // half0 takes x-col0, half1 col1
        wi0a[p].y = sb * w_ih_l0[rb * 2 + half];
        zb0p[p].x = half ? 0.f : sa * (b_ih_l0[ra] + b_hh_l0[ra]);
        zb0p[p].y = half ? 0.f : sb * (b_ih_l0[rb] + b_hh_l0[rb]);
        zb1p[p].x = half ? 0.f : sa * (b_ih_l1[ra] + b_hh_l1[ra]);
        zb1p[p].y = half ? 0.f : sb * (b_ih_l1[rb] + b_hh_l1[rb]);
#pragma unroll
        for (int kp = 0; kp < 4; ++kp) {
            const int k = half * 4 + kp;
            wh0p[p][kp].x = sa * w_hh_l0[ra * 8 + k]; wh0p[p][kp].y = sb * w_hh_l0[rb * 8 + k];
            wi1p[p][kp].x = sa * w_ih_l1[ra * 8 + k]; wi1p[p][kp].y = sb * w_ih_l1[rb * 8 + k];
            wh1p[p][kp].x = sa * w_hh_l1[ra * 8 + k]; wh1p[p][kp].y = sb * w_hh_l1[rb * 8 + k];
        }
    }
    // Pin in VGPRs (round-3 lesson: compiler otherwise sinks weight loads into the loop).
#pragma unroll
    for (int p = 0; p < 2; ++p) {
        asm volatile("" : "+v"(wi0a[p]), "+v"(zb0p[p]), "+v"(zb1p[p]));
#pragma unroll
        for (int kp = 0; kp < 4; ++kp)
            asm volatile("" : "+v"(wh0p[p][kp]), "+v"(wi1p[p][kp]), "+v"(wh1p[p][kp]));
    }

    // bpermute source addresses: lane (group8_base | half*4 + k'), byte-scaled.
    int bpa[4];
#pragma unroll
    for (int kp = 0; kp < 4; ++kp) bpa[kp] = ((lane & 0x38) | (half * 4 + kp)) << 2;

    const float fcw = fc_w[j];
    const float fcb = fc_b[0];

    float h0 = 0.f, c0 = 0.f, h1 = 0.f, c1 = 0.f;
    float h0v[4], h1v[4];          // this lane's k-slice of the h broadcasts
#pragma unroll
    for (int kp = 0; kp < 4; ++kp) { h0v[kp] = 0.f; h1v[kp] = 0.f; }

    // x[t][b][half], scalar; stride between timesteps = 2*BATCH floats.
    const float* xp = x + b * 2 + half;
    float xs = xp[0];
    float xn = xp[2 * BATCH];

    for (int t = 0; t < TSTEPS; ++t) {
        float xn2 = (t + 2 < TSTEPS) ? xp[4 * BATCH] : xs;   // 2-deep prefetch
        xp += 2 * BATCH;

        // Partial z (own k-slice). h0v/h1v carried from previous iteration.
        f32x2 z0p[2], z1p[2];
#pragma unroll
        for (int p = 0; p < 2; ++p) {
            z0p[p] = fma2(wi0a[p], splat2(xs), zb0p[p]);
            z1p[p] = zb1p[p];
#pragma unroll
            for (int kp = 0; kp < 4; ++kp) {
                z0p[p] = fma2(wh0p[p][kp], splat2(h0v[kp]), z0p[p]);
                z1p[p] = fma2(wh1p[p][kp], splat2(h1v[kp]), z1p[p]);
            }
        }
        // Combine halves: z0 full on both halves.
#pragma unroll
        for (int p = 0; p < 2; ++p) z0p[p] = z0p[p] + swz_xor8_2(z0p[p]);

        const float gi = sig_s(z0p[0].x), gf = sig_s(z0p[0].y);
        const float gg = tanh_s(z0p[1].x), go = sig_s(z0p[1].y);
        c0 = __builtin_fmaf(gf, c0, gi * gg);
        h0 = go * tanh_raw(c0);

        // Gather this lane's 4 h0 values (each 8-group holds a full h replica).
#pragma unroll
        for (int kp = 0; kp < 4; ++kp) h0v[kp] = bperm(bpa[kp], h0);

#pragma unroll
        for (int p = 0; p < 2; ++p)
#pragma unroll
            for (int kp = 0; kp < 4; ++kp)
                z1p[p] = fma2(wi1p[p][kp], splat2(h0v[kp]), z1p[p]);

#pragma unroll
        for (int p = 0; p < 2; ++p) z1p[p] = z1p[p] + swz_xor8_2(z1p[p]);

        const float i1 = sig_s(z1p[0].x), f1 = sig_s(z1p[0].y);
        const float g1 = tanh_s(z1p[1].x), o1 = sig_s(z1p[1].y);
        c1 = __builtin_fmaf(f1, c1, i1 * g1);
        h1 = o1 * tanh_raw(c1);

#pragma unroll
        for (int kp = 0; kp < 4; ++kp) h1v[kp] = bperm(bpa[kp], h1);

        xs = xn; xn = xn2;
    }

    // out[b] = fc_b + sum_j fc_w[j]*h1[j]; every 8-group holds a full replica.
    float p = fcw * h1;
    p += __shfl_xor(p, 1);
    p += __shfl_xor(p, 2);
    p += __shfl_xor(p, 4);
    if ((tid & 15) == 0) out[b] = p + fcb;
}

extern "C" void kernel_launch(void* const* d_in, const int* in_sizes, int n_in,
                              void* d_out, int out_size, void* d_ws, size_t ws_size,
                              hipStream_t stream) {
    const float* x       = (const float*)d_in[0];
    const float* w_ih_l0 = (const float*)d_in[1];
    const float* w_hh_l0 = (const float*)d_in[2];
    const float* b_ih_l0 = (const float*)d_in[3];
    const float* b_hh_l0 = (const float*)d_in[4];
    const float* w_ih_l1 = (const float*)d_in[5];
    const float* w_hh_l1 = (const float*)d_in[6];
    const float* b_ih_l1 = (const float*)d_in[7];
    const float* b_hh_l1 = (const float*)d_in[8];
    const float* fc_w    = (const float*)d_in[9];
    const float* fc_b    = (const float*)d_in[10];
    float* out = (float*)d_out;

    const int threads = 256;
    const int blocks  = (BATCH * 16) / threads;  // 1024 blocks = 4096 waves = 4/SIMD
    lstm2_fused<<<blocks, threads, 0, stream>>>(
        x, w_ih_l0, w_hh_l0, b_ih_l0, b_hh_l0,
        w_ih_l1, w_hh_l1, b_ih_l1, b_hh_l1, fc_w, fc_b, out);
}

// Round 6
// 1070.374 us; speedup vs baseline: 1.0476x; 1.0476x over previous
//
#include <hip/hip_runtime.h>

#define TSTEPS 1024
#define BATCH 16384

typedef float f32x2 __attribute__((ext_vector_type(2)));

// DPP quad_perm rotate-left-by-R within each aligned 4-lane quad: lane l
// receives lane ((l+R)&3) of its quad. Pure VALU, no LDS, no waitcnt.
template<int R>
__device__ __forceinline__ float qrot(float v) {
    constexpr int ctrl = ((R) & 3) | ((((R) + 1) & 3) << 2) |
                         ((((R) + 2) & 3) << 4) | ((((R) + 3) & 3) << 6);
    return __int_as_float(__builtin_amdgcn_mov_dpp(__float_as_int(v), ctrl, 0xF, 0xF, false));
}
template<int R>
__device__ __forceinline__ f32x2 qrot2(f32x2 v) {
    f32x2 r; r.x = qrot<R>(v.x); r.y = qrot<R>(v.y); return r;
}

__device__ __forceinline__ f32x2 fma2(f32x2 a, f32x2 b, f32x2 c) {
    return __builtin_elementwise_fma(a, b, c);   // v_pk_fma_f32
}
__device__ __forceinline__ f32x2 splat2(float v) { f32x2 r; r.x = v; r.y = v; return r; }
__device__ __forceinline__ f32x2 splx(f32x2 p) { return splat2(p.x); }  // op_sel splat
__device__ __forceinline__ f32x2 sply(f32x2 p) { return splat2(p.y); }

// Activations on PRE-SCALED z (sigmoid rows folded with -log2e, tanh rows -2log2e).
__device__ __forceinline__ float sig_s(float zs) {
    return __builtin_amdgcn_rcpf(1.0f + __builtin_amdgcn_exp2f(zs));
}
__device__ __forceinline__ float tanh_s(float zs) {
    return __builtin_fmaf(2.0f, __builtin_amdgcn_rcpf(1.0f + __builtin_amdgcn_exp2f(zs)), -1.0f);
}
__device__ __forceinline__ f32x2 sig2(f32x2 z)    { f32x2 r; r.x = sig_s(z.x);  r.y = sig_s(z.y);  return r; }
__device__ __forceinline__ f32x2 tanh2_s(f32x2 z) { f32x2 r; r.x = tanh_s(z.x); r.y = tanh_s(z.y); return r; }
__device__ __forceinline__ f32x2 tanh2_raw(f32x2 c) { return tanh2_s(c * splat2(-2.88539008f)); }

// 4 lanes per batch element; lane q owns hidden units (q, q+4) of both layers.
// All cross-lane traffic is quad_perm DPP. 1 wave/SIMD, 512-VGPR budget.
__global__ __launch_bounds__(256, 1) void lstm2_fused(
    const float* __restrict__ x,
    const float* __restrict__ w_ih_l0, const float* __restrict__ w_hh_l0,
    const float* __restrict__ b_ih_l0, const float* __restrict__ b_hh_l0,
    const float* __restrict__ w_ih_l1, const float* __restrict__ w_hh_l1,
    const float* __restrict__ b_ih_l1, const float* __restrict__ b_hh_l1,
    const float* __restrict__ fc_w, const float* __restrict__ fc_b,
    float* __restrict__ out)
{
    const int tid = blockIdx.x * blockDim.x + threadIdx.x;
    const int q   = tid & 3;     // lane-in-quad = unit pair (q, q+4)
    const int b   = tid >> 2;    // batch element

    // Gate order i,f,g,o. Pre-scale sigmoid rows by -log2e, g-gate by -2log2e.
    const float sc[4] = {-1.44269504f, -1.44269504f, -2.88539008f, -1.44269504f};

    // Weight packing: pair = (row g*8+q, row g*8+q+4). Rotation slot r supplies
    // h of source unit s=(q+r)&3 in .x and s+4 in .y, so weights are stored
    // indexed by (g, r, lo/hi) with per-lane source unit s baked in.
    f32x2 wx[4][2], zb0[4], zb1[4];
    f32x2 wh0[4][4][2], wi1[4][4][2], wh1[4][4][2];
#pragma unroll
    for (int g = 0; g < 4; ++g) {
        const int ra = g * 8 + q, rb = g * 8 + q + 4;
        const float s = sc[g];
        wx[g][0].x = s * w_ih_l0[ra * 2 + 0]; wx[g][0].y = s * w_ih_l0[rb * 2 + 0];
        wx[g][1].x = s * w_ih_l0[ra * 2 + 1]; wx[g][1].y = s * w_ih_l0[rb * 2 + 1];
        zb0[g].x = s * (b_ih_l0[ra] + b_hh_l0[ra]); zb0[g].y = s * (b_ih_l0[rb] + b_hh_l0[rb]);
        zb1[g].x = s * (b_ih_l1[ra] + b_hh_l1[ra]); zb1[g].y = s * (b_ih_l1[rb] + b_hh_l1[rb]);
#pragma unroll
        for (int r = 0; r < 4; ++r) {
            const int sl = (q + r) & 3;
            wh0[g][r][0].x = s * w_hh_l0[ra * 8 + sl];     wh0[g][r][0].y = s * w_hh_l0[rb * 8 + sl];
            wh0[g][r][1].x = s * w_hh_l0[ra * 8 + sl + 4]; wh0[g][r][1].y = s * w_hh_l0[rb * 8 + sl + 4];
            wi1[g][r][0].x = s * w_ih_l1[ra * 8 + sl];     wi1[g][r][0].y = s * w_ih_l1[rb * 8 + sl];
            wi1[g][r][1].x = s * w_ih_l1[ra * 8 + sl + 4]; wi1[g][r][1].y = s * w_ih_l1[rb * 8 + sl + 4];
            wh1[g][r][0].x = s * w_hh_l1[ra * 8 + sl];     wh1[g][r][0].y = s * w_hh_l1[rb * 8 + sl];
            wh1[g][r][1].x = s * w_hh_l1[ra * 8 + sl + 4]; wh1[g][r][1].y = s * w_hh_l1[rb * 8 + sl + 4];
        }
    }
    // Pin weights live in registers across the loop (budget 512 @ 1 wave/EU).
#pragma unroll
    for (int g = 0; g < 4; ++g) {
        asm volatile("" : "+v"(wx[g][0]), "+v"(wx[g][1]), "+v"(zb0[g]), "+v"(zb1[g]));
#pragma unroll
        for (int r = 0; r < 4; ++r)
            asm volatile("" : "+v"(wh0[g][r][0]), "+v"(wh0[g][r][1]),
                             "+v"(wi1[g][r][0]), "+v"(wi1[g][r][1]),
                             "+v"(wh1[g][r][0]), "+v"(wh1[g][r][1]));
    }

    f32x2 fcw; fcw.x = fc_w[q]; fcw.y = fc_w[q + 4];
    const float fcb = fc_b[0];

    f32x2 h0p = splat2(0.f), c0p = splat2(0.f), h1p = splat2(0.f), c1p = splat2(0.f);
    f32x2 R0[4], R1[4];          // rotated h pairs, [0] = own pair
#pragma unroll
    for (int r = 0; r < 4; ++r) { R0[r] = splat2(0.f); R1[r] = splat2(0.f); }

    const float2* xp = reinterpret_cast<const float2*>(x) + b;
    float2 xv = xp[0];
    float2 xn = xp[BATCH];

    for (int t = 0; t < TSTEPS; ++t) {
        float2 xn2 = (t + 2 < TSTEPS) ? xp[2 * BATCH] : xv;   // 2-deep prefetch
        xp += BATCH;

        // ---- Layer 0 z (uses R0 = rotated h0 from previous step), 2 partials.
        f32x2 za[4], zbq[4];
#pragma unroll
        for (int g = 0; g < 4; ++g) {
            za[g] = fma2(wx[g][1], splat2(xv.y), fma2(wx[g][0], splat2(xv.x), zb0[g]));
            za[g] = fma2(wh0[g][0][0], splx(R0[0]), za[g]);
            za[g] = fma2(wh0[g][0][1], sply(R0[0]), za[g]);
            za[g] = fma2(wh0[g][1][0], splx(R0[1]), za[g]);
            za[g] = fma2(wh0[g][1][1], sply(R0[1]), za[g]);
            zbq[g] =      wh0[g][2][0] * splx(R0[2]);
            zbq[g] = fma2(wh0[g][2][1], sply(R0[2]), zbq[g]);
            zbq[g] = fma2(wh0[g][3][0], splx(R0[3]), zbq[g]);
            zbq[g] = fma2(wh0[g][3][1], sply(R0[3]), zbq[g]);
        }
        // ---- Layer 1 recurrent (h1) part early — independent of layer-0 acts.
        f32x2 ya[4], yb[4];
#pragma unroll
        for (int g = 0; g < 4; ++g) {
            ya[g] = fma2(wh1[g][0][0], splx(R1[0]), zb1[g]);
            ya[g] = fma2(wh1[g][0][1], sply(R1[0]), ya[g]);
            ya[g] = fma2(wh1[g][1][0], splx(R1[1]), ya[g]);
            ya[g] = fma2(wh1[g][1][1], sply(R1[1]), ya[g]);
            yb[g] =      wh1[g][2][0] * splx(R1[2]);
            yb[g] = fma2(wh1[g][2][1], sply(R1[2]), yb[g]);
            yb[g] = fma2(wh1[g][3][0], splx(R1[3]), yb[g]);
            yb[g] = fma2(wh1[g][3][1], sply(R1[3]), yb[g]);
        }
        // ---- Layer 0 activations & state.
        f32x2 z0i = za[0] + zbq[0], z0f = za[1] + zbq[1];
        f32x2 z0g = za[2] + zbq[2], z0o = za[3] + zbq[3];
        c0p = fma2(sig2(z0f), c0p, sig2(z0i) * tanh2_s(z0g));
        h0p = sig2(z0o) * tanh2_raw(c0p);

        R0[0] = h0p; R0[1] = qrot2<1>(h0p); R0[2] = qrot2<2>(h0p); R0[3] = qrot2<3>(h0p);

        // ---- Layer 1 input (h0-new) part, 2 partials to shorten post-DPP path.
#pragma unroll
        for (int g = 0; g < 4; ++g) {
            f32x2 pa, pb;
            pa =      wi1[g][0][0] * splx(R0[0]);
            pa = fma2(wi1[g][0][1], sply(R0[0]), pa);
            pa = fma2(wi1[g][1][0], splx(R0[1]), pa);
            pa = fma2(wi1[g][1][1], sply(R0[1]), pa);
            pb =      wi1[g][2][0] * splx(R0[2]);
            pb = fma2(wi1[g][2][1], sply(R0[2]), pb);
            pb = fma2(wi1[g][3][0], splx(R0[3]), pb);
            pb = fma2(wi1[g][3][1], sply(R0[3]), pb);
            ya[g] = (ya[g] + yb[g]) + (pa + pb);   // full z1[g]
        }
        c1p = fma2(sig2(ya[1]), c1p, sig2(ya[0]) * tanh2_s(ya[2]));
        h1p = sig2(ya[3]) * tanh2_raw(c1p);

        R1[0] = h1p; R1[1] = qrot2<1>(h1p); R1[2] = qrot2<2>(h1p); R1[3] = qrot2<3>(h1p);

        xv = xn; xn = xn2;
    }

    // out[b] = fc_b + sum_u fc_w[u] * h1[u]; quad holds all 8 units.
    float p = __builtin_fmaf(fcw.y, h1p.y, fcw.x * h1p.x);
    p += __shfl_xor(p, 1);
    p += __shfl_xor(p, 2);
    if ((tid & 3) == 0) out[b] = p + fcb;
}

extern "C" void kernel_launch(void* const* d_in, const int* in_sizes, int n_in,
                              void* d_out, int out_size, void* d_ws, size_t ws_size,
                              hipStream_t stream) {
    const float* x       = (const float*)d_in[0];
    const float* w_ih_l0 = (const float*)d_in[1];
    const float* w_hh_l0 = (const float*)d_in[2];
    const float* b_ih_l0 = (const float*)d_in[3];
    const float* b_hh_l0 = (const float*)d_in[4];
    const float* w_ih_l1 = (const float*)d_in[5];
    const float* w_hh_l1 = (const float*)d_in[6];
    const float* b_ih_l1 = (const float*)d_in[7];
    const float* b_hh_l1 = (const float*)d_in[8];
    const float* fc_w    = (const float*)d_in[9];
    const float* fc_b    = (const float*)d_in[10];
    float* out = (float*)d_out;

    const int threads = 256;
    const int blocks  = (BATCH * 4) / threads;   // 256 blocks = 1024 waves = 1/SIMD
    lstm2_fused<<<blocks, threads, 0, stream>>>(
        x, w_ih_l0, w_hh_l0, b_ih_l0, b_hh_l0,
        w_ih_l1, w_hh_l1, b_ih_l1, b_hh_l1, fc_w, fc_b, out);
}